// Round 3
// baseline (260.816 us; speedup 1.0000x reference)
//
#include <hip/hip_runtime.h>
#include <hip/hip_fp16.h>

// ProtoNet distance matrix: out[n,k] = (alpha+1e-16)^2 * (||x_n||^2 + ||p_k||^2 - 2 x_n.p_k)
// x: [16384,1024] f32, p: [2048,1024] f32, alpha: [1] f32, out: [16384,2048] f32.
//
// Strategy: no fp32 MFMA on CDNA4 -> convert to fp16 once (cross-term error
// ~3e-5 of absmax; row-norms kept exact fp32), then cross-term GEMM on
// v_mfma_f32_16x16x32_f16. GEMM: 128x128 tile, BK=64, 4 waves (2x2),
// double-buffered LDS via global_load_lds width=16, XOR-swizzled LDS
// (slot ^= row&7) realized by pre-swizzling the GLOBAL source addresses
// (LDS dest must stay linear: uniform base + lane*16).
//
// Safety: fast path needs ~36.1 MB of d_ws. If ws_size is smaller, fall back
// to a direct fp32 kernel (host-side constant branch — graph-capture safe).

#define N_ROWS 16384
#define K_PROTO 2048
#define DIM 1024

#define BM 128
#define BN 128
#define BK 64
#define NT (DIM / BK)  // 16 K-steps

typedef _Float16 half8 __attribute__((ext_vector_type(8)));
typedef float f32x4 __attribute__((ext_vector_type(4)));

__device__ __forceinline__ void async_copy16(void* lds_dst, const void* g_src) {
    __builtin_amdgcn_global_load_lds(
        (const __attribute__((address_space(1))) void*)g_src,
        (__attribute__((address_space(3))) void*)lds_dst,
        16, 0, 0);
}

// ---------------- Pass 1: convert + row sum-of-squares ----------------
// One block per row. Rows [0,16384) = x, [16384, 18432) = p.
__global__ __launch_bounds__(256) void convert_kernel(
    const float* __restrict__ x, const float* __restrict__ p,
    __half* __restrict__ xh, __half* __restrict__ ph,
    float* __restrict__ xsq, float* __restrict__ psq)
{
    int row = blockIdx.x;
    const float* src;
    __half* dst;
    float* sq;
    if (row < N_ROWS) {
        src = x + (size_t)row * DIM;
        dst = xh + (size_t)row * DIM;
        sq = xsq + row;
    } else {
        int r = row - N_ROWS;
        src = p + (size_t)r * DIM;
        dst = ph + (size_t)r * DIM;
        sq = psq + r;
    }
    int t = threadIdx.x;  // 256 threads, 4 floats each = 1024
    float4 v = reinterpret_cast<const float4*>(src)[t];
    float s = v.x * v.x + v.y * v.y + v.z * v.z + v.w * v.w;

    union { __half2 h[2]; uint2 u; } pk;
    pk.h[0] = __floats2half2_rn(v.x, v.y);
    pk.h[1] = __floats2half2_rn(v.z, v.w);
    reinterpret_cast<uint2*>(dst)[t] = pk.u;

    // wave reduce (64 lanes) then cross-wave via LDS
    #pragma unroll
    for (int off = 32; off > 0; off >>= 1) s += __shfl_down(s, off);
    __shared__ float red[4];
    if ((t & 63) == 0) red[t >> 6] = s;
    __syncthreads();
    if (t == 0) sq[0] = red[0] + red[1] + red[2] + red[3];
}

// ---------------- Pass 2: fp16 MFMA GEMM + fused epilogue ----------------
// grid = (16384/128)*(2048/128) = 2048 blocks, 256 threads (4 waves, 2x2).
// LDS per buffer: A[128][64] f16 (16KB) + B[128][64] f16 (16KB); x2 dbuf = 64KB.
// Row = 128B = 8 x 16B slots. Physical slot ps of row r holds logical slot
// s = ps ^ (r&7) (involution). Staging pre-swizzles the SOURCE address;
// reads apply the same XOR. Read-side distribution: ps = (kk*4+q)^(rr&7)
// puts exactly 8 of 64 lanes on each 16B slot group -> conflict-free b128.

__global__ __launch_bounds__(256, 2) void gemm_kernel(
    const __half* __restrict__ xh, const __half* __restrict__ ph,
    const float* __restrict__ xsq, const float* __restrict__ psq,
    const float* __restrict__ alpha, float* __restrict__ out)
{
    __shared__ __align__(1024) char lds[2][2 * BM * BK * 2];  // [buf][A(16KB)|B(16KB)]

    const int tid = threadIdx.x;
    const int w = tid >> 6;      // wave 0..3
    const int lane = tid & 63;
    const int wr = w >> 1;       // wave row 0..1 (64 rows each)
    const int wc = w & 1;        // wave col 0..1 (64 cols each)
    const int rr = lane & 15;    // fragment row/col within 16
    const int q = lane >> 4;     // k-quad 0..3

    const int bm = blockIdx.x >> 4;   // 0..127  (x panel)
    const int bn = blockIdx.x & 15;   // 0..15   (p panel)

    const int c0 = w * 64 + lane;     // base chunk for i=0 (stride 256 per i)
    f32x4 acc[4][4];
    #pragma unroll
    for (int m = 0; m < 4; ++m)
        #pragma unroll
        for (int n = 0; n < 4; ++n)
            acc[m][n] = (f32x4)0.0f;

    auto stage = [&](int buf, int kt) {
        char* base = lds[buf];
        #pragma unroll
        for (int i = 0; i < 4; ++i) {
            int c = i * 256 + c0;          // 0..1023
            int r = c >> 3;                // tile row 0..127
            int ps = c & 7;                // physical 16B slot
            int s = ps ^ (r & 7);          // logical slot (XOR swizzle)
            const __half* srcA = xh + (size_t)(bm * BM + r) * DIM + kt * BK + s * 8;
            async_copy16(base + (i * 4 + w) * 1024, srcA);
        }
        #pragma unroll
        for (int i = 0; i < 4; ++i) {
            int c = i * 256 + c0;
            int r = c >> 3;
            int ps = c & 7;
            int s = ps ^ (r & 7);
            const __half* srcB = ph + (size_t)(bn * BN + r) * DIM + kt * BK + s * 8;
            async_copy16(base + 16384 + (i * 4 + w) * 1024, srcB);
        }
    };

    stage(0, 0);
    __syncthreads();

    int cur = 0;
    for (int kt = 0; kt < NT; ++kt) {
        if (kt + 1 < NT) stage(cur ^ 1, kt + 1);

        const char* Ab = lds[cur];
        const char* Bb = lds[cur] + 16384;
        #pragma unroll
        for (int kk = 0; kk < 2; ++kk) {
            half8 af[4], bf[4];
            #pragma unroll
            for (int m = 0; m < 4; ++m) {
                int row = wr * 64 + m * 16 + rr;
                int slot = kk * 4 + q;
                af[m] = *(const half8*)(Ab + row * 128 + ((slot ^ (row & 7)) * 16));
            }
            #pragma unroll
            for (int n = 0; n < 4; ++n) {
                int row = wc * 64 + n * 16 + rr;
                int slot = kk * 4 + q;
                bf[n] = *(const half8*)(Bb + row * 128 + ((slot ^ (row & 7)) * 16));
            }
            #pragma unroll
            for (int m = 0; m < 4; ++m)
                #pragma unroll
                for (int n = 0; n < 4; ++n)
                    acc[m][n] = __builtin_amdgcn_mfma_f32_16x16x32_f16(
                        af[m], bf[n], acc[m][n], 0, 0, 0);
        }
        __syncthreads();
        cur ^= 1;
    }

    // epilogue: out = scale * (xsq[row] + psq[col] - 2*cross)
    const float a = alpha[0] + 1e-16f;
    const float scale = a * a;
    #pragma unroll
    for (int n = 0; n < 4; ++n) {
        int col = bn * BN + wc * 64 + n * 16 + rr;
        float pv = psq[col];
        #pragma unroll
        for (int m = 0; m < 4; ++m) {
            int rowbase = bm * BM + wr * 64 + m * 16 + q * 4;
            #pragma unroll
            for (int r = 0; r < 4; ++r) {
                int row = rowbase + r;
                out[(size_t)row * K_PROTO + col] =
                    scale * (xsq[row] + pv - 2.0f * acc[m][n][r]);
            }
        }
    }
}

// ---------------- Fallback: direct fp32, no workspace ----------------
// One block per x-row; x-row staged in LDS; each thread computes 8 protos.
// Correct-by-construction; only used if ws_size is too small for fast path.
__global__ __launch_bounds__(256) void fallback_kernel(
    const float* __restrict__ x, const float* __restrict__ p,
    const float* __restrict__ alpha, float* __restrict__ out)
{
    __shared__ float xs[DIM];
    int n = blockIdx.x;
    int t = threadIdx.x;
    reinterpret_cast<float4*>(xs)[t] = reinterpret_cast<const float4*>(x + (size_t)n * DIM)[t];
    __syncthreads();
    const float a = alpha[0] + 1e-16f;
    const float scale = a * a;
    for (int j = 0; j < K_PROTO / 256; ++j) {
        int k = j * 256 + t;
        const float4* pr = reinterpret_cast<const float4*>(p + (size_t)k * DIM);
        float s = 0.0f;
        #pragma unroll 8
        for (int d4 = 0; d4 < DIM / 4; ++d4) {
            float4 pv = pr[d4];
            float dx = xs[d4 * 4 + 0] - pv.x;
            float dy = xs[d4 * 4 + 1] - pv.y;
            float dz = xs[d4 * 4 + 2] - pv.z;
            float dw = xs[d4 * 4 + 3] - pv.w;
            s += dx * dx + dy * dy + dz * dz + dw * dw;
        }
        out[(size_t)n * K_PROTO + k] = scale * s;
    }
}

extern "C" void kernel_launch(void* const* d_in, const int* in_sizes, int n_in,
                              void* d_out, int out_size, void* d_ws, size_t ws_size,
                              hipStream_t stream) {
    const float* x = (const float*)d_in[0];
    const float* p = (const float*)d_in[1];
    const float* alpha = (const float*)d_in[2];
    float* out = (float*)d_out;

    // workspace layout (~36.1 MB): xh | ph | xsq | psq
    const size_t XH_BYTES = (size_t)N_ROWS * DIM * sizeof(__half);   // 32 MB
    const size_t PH_BYTES = (size_t)K_PROTO * DIM * sizeof(__half);  // 4 MB
    const size_t NEED = XH_BYTES + PH_BYTES +
                        (size_t)(N_ROWS + K_PROTO) * sizeof(float);

    if (ws_size < NEED) {
        fallback_kernel<<<dim3(N_ROWS), dim3(256), 0, stream>>>(x, p, alpha, out);
        return;
    }

    char* w = (char*)d_ws;
    __half* xh = (__half*)w;
    __half* ph = (__half*)(w + XH_BYTES);
    float* xsq = (float*)(w + XH_BYTES + PH_BYTES);
    float* psq = (float*)(w + XH_BYTES + PH_BYTES + N_ROWS * sizeof(float));

    convert_kernel<<<dim3(N_ROWS + K_PROTO), dim3(256), 0, stream>>>(
        x, p, xh, ph, xsq, psq);
    gemm_kernel<<<dim3((N_ROWS / BM) * (K_PROTO / BN)), dim3(256), 0, stream>>>(
        xh, ph, xsq, psq, alpha, out);
}